// Round 6
// baseline (1490.103 us; speedup 1.0000x reference)
//
#include <hip/hip_runtime.h>

// Problem constants (from reference setup_inputs)
constexpr int Bsz   = 1024;     // batch
constexpr int F0    = 20000;    // input features
constexpr int NOUT0 = 5000, NOUT1 = 1000, NOUT2 = 256;
constexpr int NE0   = 100000, NE1 = 50000, NE2 = 10000;
constexpr int NE_TOT = NE0 + NE1 + NE2;         // 160000
constexpr int NSRC0  = 20000;                    // src bins for layer 0
constexpr int CNT_N  = NOUT0 + NOUT1 + NOUT2;   // 6256
constexpr int G0     = 8;                        // src rows per l0_scatter block
constexpr int MAXIDX = 512;                      // max edges per dst bucket staged

// ---------------------------------------------------------------------------
// Transpose data (B, F0) -> dataT (F0, B), fused with *p0 row scale.
// 64x64 tile, float4 on both global sides.
__global__ __launch_bounds__(256) void transpose_scale(
    const float* __restrict__ data, const float* __restrict__ p0,
    float* __restrict__ dataT)
{
    __shared__ float tile[64][65];
    const int t  = threadIdx.x;
    const int c0 = blockIdx.x * 64;   // F0 dim
    const int r0 = blockIdx.y * 64;   // B dim

    const int f4 = t & 15;
    const int rr = t >> 4;
    const int col = c0 + f4 * 4;
    if (col < F0) {
#pragma unroll
        for (int p = 0; p < 4; ++p) {
            const int br = rr + p * 16;
            const float4 v = *(const float4*)&data[(size_t)(r0 + br) * F0 + col];
            tile[br][f4 * 4 + 0] = v.x;
            tile[br][f4 * 4 + 1] = v.y;
            tile[br][f4 * 4 + 2] = v.z;
            tile[br][f4 * 4 + 3] = v.w;
        }
    }
    __syncthreads();

    const int b4 = t & 15;
    const int fr = t >> 4;
#pragma unroll
    for (int p = 0; p < 4; ++p) {
        const int f = c0 + fr + p * 16;
        if (f < F0) {
            const float s = p0[f];
            float4 v;
            v.x = tile[b4 * 4 + 0][fr + p * 16] * s;
            v.y = tile[b4 * 4 + 1][fr + p * 16] * s;
            v.z = tile[b4 * 4 + 2][fr + p * 16] * s;
            v.w = tile[b4 * 4 + 3][fr + p * 16] * s;
            *(float4*)&dataT[(size_t)f * Bsz + r0 + b4 * 4] = v;
        }
    }
}

// ---------------------------------------------------------------------------
// Counting: cnt[6256] = dst in-degrees (for mean + CSR of layers 1,2);
//           cnt_src[20000] = src out-degrees of layer 0 (for src-CSR).
__global__ __launch_bounds__(256) void count_all(
    const int* __restrict__ src0, const int* __restrict__ dst0,
    const int* __restrict__ dst1, const int* __restrict__ dst2,
    int* __restrict__ cnt, int* __restrict__ cnt_src)
{
    const int i = blockIdx.x * 256 + threadIdx.x;
    if (i < NE0) {
        atomicAdd(&cnt_src[src0[i]], 1);
        atomicAdd(&cnt[dst0[i]], 1);
    } else if (i < NE0 + NE1) {
        atomicAdd(&cnt[NOUT0 + dst1[i - NE0]], 1);
    } else if (i < NE_TOT) {
        atomicAdd(&cnt[NOUT0 + NOUT1 + dst2[i - NE0 - NE1]], 1);
    }
}

// Block 0: scan src0 counts (n=20000); block 1: dst1 (1000); block 2: dst2 (256);
// block 3: g0[j] = p1[j] / max(cnt0[j],1)  (layer-0 mean + p1 fused prescale).
__global__ __launch_bounds__(1024) void scan4(
    const int* __restrict__ cnt, const int* __restrict__ cnt_src,
    int* __restrict__ offs_src, int* __restrict__ offs1, int* __restrict__ offs2,
    int* __restrict__ cur_src,  int* __restrict__ cur1,  int* __restrict__ cur2,
    const float* __restrict__ p1, float* __restrict__ g0)
{
    const int L = blockIdx.x;
    const int t = threadIdx.x;
    if (L == 3) {
        for (int j = t; j < NOUT0; j += 1024)
            g0[j] = p1[j] / fmaxf((float)cnt[j], 1.0f);
        return;
    }
    int n; const int* c; int* ofs; int* cur;
    if (L == 0)      { n = NSRC0; c = cnt_src;               ofs = offs_src; cur = cur_src; }
    else if (L == 1) { n = NOUT1; c = cnt + NOUT0;           ofs = offs1;    cur = cur1; }
    else             { n = NOUT2; c = cnt + NOUT0 + NOUT1;   ofs = offs2;    cur = cur2; }

    __shared__ int lds[1024];
    constexpr int CH = 20;                 // 1024*20 = 20480 >= 20000
    const int base = t * CH;
    int vals[CH];
    int local = 0;
#pragma unroll
    for (int k = 0; k < CH; ++k) {
        const int i = base + k;
        const int v = (i < n) ? c[i] : 0;
        vals[k] = v;
        local += v;
    }
    lds[t] = local;
    __syncthreads();
    for (int d = 1; d < 1024; d <<= 1) {
        const int v = (t >= d) ? lds[t - d] : 0;
        __syncthreads();
        lds[t] += v;
        __syncthreads();
    }
    int excl = lds[t] - local;
#pragma unroll
    for (int k = 0; k < CH; ++k) {
        const int i = base + k;
        if (i < n) { ofs[i] = excl; cur[i] = excl; }
        excl += vals[k];
    }
    if (t == 1023) ofs[n] = lds[1023];
}

// csr0[.] = dst, sorted by src (layer 0); csr12[.] = src, sorted by dst (layers 1,2).
__global__ __launch_bounds__(256) void scatter_all(
    const int* __restrict__ src0, const int* __restrict__ dst0,
    const int* __restrict__ src1, const int* __restrict__ dst1,
    const int* __restrict__ src2, const int* __restrict__ dst2,
    int* __restrict__ cur_src, int* __restrict__ cur1, int* __restrict__ cur2,
    int* __restrict__ csr0, int* __restrict__ csr12)
{
    const int i = blockIdx.x * 256 + threadIdx.x;
    if (i < NE0) {
        const int pos = atomicAdd(&cur_src[src0[i]], 1);
        csr0[pos] = dst0[i];
    } else if (i < NE0 + NE1) {
        const int k = i - NE0;
        const int pos = atomicAdd(&cur1[dst1[k]], 1);
        csr12[pos] = src1[k];
    } else if (i < NE_TOT) {
        const int k = i - NE0 - NE1;
        const int pos = atomicAdd(&cur2[dst2[k]], 1);
        csr12[NE1 + pos] = src2[k];
    }
}

// ---------------------------------------------------------------------------
// Layer 0, scatter form: block owns G0 src rows; each row read ONCE (float4/thread),
// then HW fp32 atomics into y0raw[dst] rows. dataT streamed exactly once (80MB).
__global__ __launch_bounds__(256) void l0_scatter(
    const float4* __restrict__ dataT, const int* __restrict__ csr0,
    const int* __restrict__ offs_src, float* __restrict__ y0raw)
{
    const int t = threadIdx.x;
    const int s0 = blockIdx.x * G0;
#pragma unroll 1
    for (int s = s0; s < s0 + G0; ++s) {
        const int beg = offs_src[s], end = offs_src[s + 1];
        if (beg == end) continue;
        const float4 v = dataT[(size_t)s * (Bsz / 4) + t];
        for (int e = beg; e < end; ++e) {
            const int d = csr0[e];
            float* yr = y0raw + (size_t)d * Bsz + t * 4;
            unsafeAtomicAdd(yr + 0, v.x);
            unsafeAtomicAdd(yr + 1, v.y);
            unsafeAtomicAdd(yr + 2, v.z);
            unsafeAtomicAdd(yr + 3, v.w);
        }
    }
}

// ---------------------------------------------------------------------------
// Layer 1 gather with per-src prescale: x1_t[s] = relu(y0raw[s]) * g0[s];
// final write = relu(mean) * p2 (fused).
__global__ __launch_bounds__(256) void l1_gather(
    const float4* __restrict__ y0raw, const int* __restrict__ csr,
    const int* __restrict__ offs, const float* __restrict__ g0,
    const float* __restrict__ p2, float4* __restrict__ y1)
{
    __shared__ int   sidx[MAXIDX];
    __shared__ float sg[MAXIDX];
    const int j = blockIdx.x;
    const int t = threadIdx.x;
    const int beg = offs[j], end = offs[j + 1];
    const int n = end - beg;
    const int np = n < MAXIDX ? n : MAXIDX;
    for (int i = t; i < np; i += 256) {
        const int s = csr[beg + i];
        sidx[i] = s;
        sg[i] = g0[s];
    }
    __syncthreads();

    float4 a0 = make_float4(0.f, 0.f, 0.f, 0.f);
    float4 a1 = make_float4(0.f, 0.f, 0.f, 0.f);
    int e = 0;
    for (; e + 2 <= np; e += 2) {
        const int s0 = sidx[e + 0], s1 = sidx[e + 1];
        const float g0v = sg[e + 0], g1v = sg[e + 1];
        const float4 v0 = y0raw[(size_t)s0 * (Bsz / 4) + t];
        const float4 v1 = y0raw[(size_t)s1 * (Bsz / 4) + t];
        a0.x += fmaxf(v0.x, 0.f) * g0v; a0.y += fmaxf(v0.y, 0.f) * g0v;
        a0.z += fmaxf(v0.z, 0.f) * g0v; a0.w += fmaxf(v0.w, 0.f) * g0v;
        a1.x += fmaxf(v1.x, 0.f) * g1v; a1.y += fmaxf(v1.y, 0.f) * g1v;
        a1.z += fmaxf(v1.z, 0.f) * g1v; a1.w += fmaxf(v1.w, 0.f) * g1v;
    }
    if (e < np) {
        const float4 v = y0raw[(size_t)sidx[e] * (Bsz / 4) + t];
        const float gv = sg[e];
        a0.x += fmaxf(v.x, 0.f) * gv; a0.y += fmaxf(v.y, 0.f) * gv;
        a0.z += fmaxf(v.z, 0.f) * gv; a0.w += fmaxf(v.w, 0.f) * gv;
    }
    a0.x += a1.x; a0.y += a1.y; a0.z += a1.z; a0.w += a1.w;

    const float sc = p2[j] / fmaxf((float)n, 1.0f);
    float4 r;
    r.x = fmaxf(a0.x, 0.f) * sc;
    r.y = fmaxf(a0.y, 0.f) * sc;
    r.z = fmaxf(a0.z, 0.f) * sc;
    r.w = fmaxf(a0.w, 0.f) * sc;
    y1[(size_t)j * (Bsz / 4) + t] = r;
}

// Layer 2 gather (plain; y1 already holds relu(mean)*p2 values).
__global__ __launch_bounds__(256) void l2_gather(
    const float4* __restrict__ xT, const int* __restrict__ csr,
    const int* __restrict__ offs, float4* __restrict__ yT)
{
    __shared__ int sidx[MAXIDX];
    const int j = blockIdx.x;
    const int t = threadIdx.x;
    const int beg = offs[j], end = offs[j + 1];
    const int n = end - beg;
    const int np = n < MAXIDX ? n : MAXIDX;
    for (int i = t; i < np; i += 256) sidx[i] = csr[beg + i];
    __syncthreads();

    float4 a0 = make_float4(0.f, 0.f, 0.f, 0.f);
    float4 a1 = make_float4(0.f, 0.f, 0.f, 0.f);
    int e = 0;
    for (; e + 2 <= np; e += 2) {
        const float4 v0 = xT[(size_t)sidx[e + 0] * (Bsz / 4) + t];
        const float4 v1 = xT[(size_t)sidx[e + 1] * (Bsz / 4) + t];
        a0.x += v0.x; a0.y += v0.y; a0.z += v0.z; a0.w += v0.w;
        a1.x += v1.x; a1.y += v1.y; a1.z += v1.z; a1.w += v1.w;
    }
    if (e < np) {
        const float4 v = xT[(size_t)sidx[e] * (Bsz / 4) + t];
        a0.x += v.x; a0.y += v.y; a0.z += v.z; a0.w += v.w;
    }
    a0.x += a1.x; a0.y += a1.y; a0.z += a1.z; a0.w += a1.w;

    const float inv = 1.0f / fmaxf((float)n, 1.0f);
    float4 r;
    r.x = fmaxf(a0.x * inv, 0.f);
    r.y = fmaxf(a0.y * inv, 0.f);
    r.z = fmaxf(a0.z * inv, 0.f);
    r.w = fmaxf(a0.w * inv, 0.f);
    yT[(size_t)j * (Bsz / 4) + t] = r;
}

// ---------------------------------------------------------------------------
// Head: out (B,10) = y2 (B,256) @ W.T + b, y2 stored transposed.
__global__ __launch_bounds__(256) void head_gemm(
    const float* __restrict__ y2T, const float* __restrict__ W,
    const float* __restrict__ bias, float* __restrict__ out)
{
    __shared__ float ws[10 * 256];
    __shared__ float bs[10];
    const int t = threadIdx.x;
    for (int i = t; i < 10 * 256; i += 256) ws[i] = W[i];
    if (t < 10) bs[t] = bias[t];
    __syncthreads();

    const int b = blockIdx.x * 256 + t;
    float acc[10];
#pragma unroll
    for (int o = 0; o < 10; ++o) acc[o] = bs[o];
    for (int k = 0; k < 256; ++k) {
        const float v = y2T[(size_t)k * Bsz + b];
#pragma unroll
        for (int o = 0; o < 10; ++o) acc[o] += v * ws[o * 256 + k];
    }
#pragma unroll
    for (int o = 0; o < 10; ++o) out[(size_t)b * 10 + o] = acc[o];
}

// ---------------------------------------------------------------------------
extern "C" void kernel_launch(void* const* d_in, const int* in_sizes, int n_in,
                              void* d_out, int out_size, void* d_ws, size_t ws_size,
                              hipStream_t stream)
{
    const float* data = (const float*)d_in[0];
    const float* p0   = (const float*)d_in[1];
    const float* p1   = (const float*)d_in[2];
    const float* p2   = (const float*)d_in[3];
    const float* W    = (const float*)d_in[4];
    const float* bias = (const float*)d_in[5];
    const int* src0 = (const int*)d_in[6];
    const int* dst0 = (const int*)d_in[7];
    const int* src1 = (const int*)d_in[8];
    const int* dst1 = (const int*)d_in[9];
    const int* src2 = (const int*)d_in[10];
    const int* dst2 = (const int*)d_in[11];

    char* ws = (char*)d_ws;
    auto align = [](size_t x) { return (x + 255) & ~size_t(255); };
    size_t o = 0;
    // --- zero zone (one memset): cnt, cnt_src, y0raw ---
    int* cnt      = (int*)(ws + o);  o = align(o + (size_t)CNT_N * 4);
    int* cnt_src  = (int*)(ws + o);  o = align(o + (size_t)NSRC0 * 4);
    float* y0raw  = (float*)(ws + o); o = align(o + (size_t)NOUT0 * Bsz * 4);
    const size_t zero_bytes = o;
    // --- rest ---
    float* dataT  = (float*)(ws + o); o = align(o + (size_t)F0 * Bsz * 4);
    float* y1     = (float*)(ws + o); o = align(o + (size_t)NOUT1 * Bsz * 4);
    float* y2     = (float*)(ws + o); o = align(o + (size_t)NOUT2 * Bsz * 4);
    int* offs_src = (int*)(ws + o);  o = align(o + (size_t)(NSRC0 + 1) * 4);
    int* offs1    = (int*)(ws + o);  o = align(o + (size_t)(NOUT1 + 1) * 4);
    int* offs2    = (int*)(ws + o);  o = align(o + (size_t)(NOUT2 + 1) * 4);
    int* cur_src  = (int*)(ws + o);  o = align(o + (size_t)NSRC0 * 4);
    int* cur1     = (int*)(ws + o);  o = align(o + (size_t)NOUT1 * 4);
    int* cur2     = (int*)(ws + o);  o = align(o + (size_t)NOUT2 * 4);
    int* csr0     = (int*)(ws + o);  o = align(o + (size_t)NE0 * 4);
    int* csr12    = (int*)(ws + o);  o = align(o + (size_t)(NE1 + NE2) * 4);
    float* g0     = (float*)(ws + o); o = align(o + (size_t)NOUT0 * 4);

    hipMemsetAsync(ws, 0, zero_bytes, stream);

    count_all<<<(NE_TOT + 255) / 256, 256, 0, stream>>>(src0, dst0, dst1, dst2, cnt, cnt_src);
    scan4<<<4, 1024, 0, stream>>>(cnt, cnt_src, offs_src, offs1, offs2,
                                  cur_src, cur1, cur2, p1, g0);
    scatter_all<<<(NE_TOT + 255) / 256, 256, 0, stream>>>(
        src0, dst0, src1, dst1, src2, dst2, cur_src, cur1, cur2, csr0, csr12);

    transpose_scale<<<dim3((F0 + 63) / 64, Bsz / 64), 256, 0, stream>>>(data, p0, dataT);

    l0_scatter<<<NSRC0 / G0, 256, 0, stream>>>((const float4*)dataT, csr0, offs_src, y0raw);
    l1_gather<<<NOUT1, 256, 0, stream>>>((const float4*)y0raw, csr12, offs1, g0, p2, (float4*)y1);
    l2_gather<<<NOUT2, 256, 0, stream>>>((const float4*)y1, csr12 + NE1, offs2, (float4*)y2);

    head_gemm<<<Bsz / 256, 256, 0, stream>>>(y2, W, bias, (float*)d_out);
}

// Round 7
// 142.698 us; speedup vs baseline: 10.4423x; 10.4423x over previous
//
#include <hip/hip_runtime.h>
#include <hip/hip_fp16.h>

// Problem constants (from reference setup_inputs)
constexpr int Bsz   = 1024;     // batch
constexpr int F0    = 20000;    // input features
constexpr int NOUT0 = 5000, NOUT1 = 1000, NOUT2 = 256;
constexpr int NE0   = 100000, NE1 = 50000, NE2 = 10000;
constexpr int CNT_N  = NOUT0 + NOUT1 + NOUT2;   // 6256
constexpr int OFFS_N = CNT_N + 3;               // 6259
constexpr int CSR_N  = NE0 + NE1 + NE2;         // 160000
constexpr int MAXIDX = 512;                      // max edges staged per dst

union H4 { uint2 u; __half2 h[2]; };

// ---------------------------------------------------------------------------
// Transpose data (B, F0) fp32 -> dataT (F0, B) fp16, fused with *p0 row scale.
// 64x64 tile; float4 global loads, 8B (4xhalf) global stores.
__global__ __launch_bounds__(256) void transpose_scale(
    const float* __restrict__ data, const float* __restrict__ p0,
    __half* __restrict__ dataT)
{
    __shared__ float tile[64][65];
    const int t  = threadIdx.x;
    const int c0 = blockIdx.x * 64;   // F0 dim
    const int r0 = blockIdx.y * 64;   // B dim

    const int f4 = t & 15;
    const int rr = t >> 4;
    const int col = c0 + f4 * 4;
    if (col < F0) {                   // F0 % 4 == 0 so this guard is exact
#pragma unroll
        for (int p = 0; p < 4; ++p) {
            const int br = rr + p * 16;
            const float4 v = *(const float4*)&data[(size_t)(r0 + br) * F0 + col];
            tile[br][f4 * 4 + 0] = v.x;
            tile[br][f4 * 4 + 1] = v.y;
            tile[br][f4 * 4 + 2] = v.z;
            tile[br][f4 * 4 + 3] = v.w;
        }
    }
    __syncthreads();

    const int b4 = t & 15;
    const int fr = t >> 4;
#pragma unroll
    for (int p = 0; p < 4; ++p) {
        const int f = c0 + fr + p * 16;
        if (f < F0) {
            const float s = p0[f];
            H4 o;
            o.h[0] = __floats2half2_rn(tile[b4 * 4 + 0][fr + p * 16] * s,
                                       tile[b4 * 4 + 1][fr + p * 16] * s);
            o.h[1] = __floats2half2_rn(tile[b4 * 4 + 2][fr + p * 16] * s,
                                       tile[b4 * 4 + 3][fr + p * 16] * s);
            *(uint2*)&dataT[(size_t)f * Bsz + r0 + b4 * 4] = o.u;
        }
    }
}

// ---------------------------------------------------------------------------
// CSR build: count, scan, scatter (all 3 layers at once) — round-4 machinery.
__global__ __launch_bounds__(256) void count_edges(
    const int* __restrict__ dst0, const int* __restrict__ dst1,
    const int* __restrict__ dst2, int* __restrict__ cnt)
{
    const int i = blockIdx.x * 256 + threadIdx.x;
    if (i < NE0)                 atomicAdd(&cnt[dst0[i]], 1);
    else if (i < NE0 + NE1)      atomicAdd(&cnt[NOUT0 + dst1[i - NE0]], 1);
    else if (i < NE0 + NE1 + NE2) atomicAdd(&cnt[NOUT0 + NOUT1 + dst2[i - NE0 - NE1]], 1);
}

__global__ __launch_bounds__(1024) void scan_offs(
    const int* __restrict__ cnt, int* __restrict__ offs, int* __restrict__ cursor)
{
    const int L = blockIdx.x;
    const int nout  = (L == 0) ? NOUT0 : (L == 1) ? NOUT1 : NOUT2;
    const int cbase = (L == 0) ? 0 : (L == 1) ? NOUT0 : NOUT0 + NOUT1;
    const int obase = (L == 0) ? 0 : (L == 1) ? NOUT0 + 1 : NOUT0 + NOUT1 + 2;
    const int* c  = cnt + cbase;
    int* ofs      = offs + obase;
    int* cur      = cursor + cbase;

    __shared__ int lds[1024];
    const int t = threadIdx.x;
    constexpr int CHUNK = 5;              // covers nout <= 5120
    const int base = t * CHUNK;
    int vals[CHUNK];
    int local = 0;
#pragma unroll
    for (int k = 0; k < CHUNK; ++k) {
        const int i = base + k;
        const int v = (i < nout) ? c[i] : 0;
        vals[k] = v;
        local += v;
    }
    lds[t] = local;
    __syncthreads();
    for (int d = 1; d < 1024; d <<= 1) {
        const int v = (t >= d) ? lds[t - d] : 0;
        __syncthreads();
        lds[t] += v;
        __syncthreads();
    }
    int excl = lds[t] - local;
#pragma unroll
    for (int k = 0; k < CHUNK; ++k) {
        const int i = base + k;
        if (i < nout) { ofs[i] = excl; cur[i] = excl; }
        excl += vals[k];
    }
    if (t == 1023) ofs[nout] = lds[1023];
}

__global__ __launch_bounds__(256) void scatter_edges(
    const int* __restrict__ src0, const int* __restrict__ dst0,
    const int* __restrict__ src1, const int* __restrict__ dst1,
    const int* __restrict__ src2, const int* __restrict__ dst2,
    int* __restrict__ cursor, int* __restrict__ csr)
{
    const int i = blockIdx.x * 256 + threadIdx.x;
    if (i < NE0) {
        const int pos = atomicAdd(&cursor[dst0[i]], 1);
        csr[pos] = src0[i];
    } else if (i < NE0 + NE1) {
        const int k = i - NE0;
        const int pos = atomicAdd(&cursor[NOUT0 + dst1[k]], 1);
        csr[NE0 + pos] = src1[k];
    } else if (i < NE0 + NE1 + NE2) {
        const int k = i - NE0 - NE1;
        const int pos = atomicAdd(&cursor[NOUT0 + NOUT1 + dst2[k]], 1);
        csr[NE0 + NE1 + pos] = src2[k];
    }
}

// ---------------------------------------------------------------------------
// One layer (fp16 I/O, fp32 accumulate): block j sums rows xT[csr[e]],
// relu(mean)*pnext fused, written transposed as fp16.
// Thread t owns batch columns [t*4, t*4+4): 8B loads/stores, fully coalesced.
__global__ __launch_bounds__(256) void layer_fwd(
    const __half* __restrict__ xT, const int* __restrict__ csr,
    const int* __restrict__ offs, const float* __restrict__ pnext,
    __half* __restrict__ yT)
{
    __shared__ int sidx[MAXIDX];
    const int j = blockIdx.x;
    const int t = threadIdx.x;
    const int beg = offs[j], end = offs[j + 1];
    const int n = end - beg;
    const int np = n < MAXIDX ? n : MAXIDX;
    for (int i = t; i < np; i += 256) sidx[i] = csr[beg + i];
    __syncthreads();

    const int c = t * 4;
    float4 a0 = make_float4(0.f, 0.f, 0.f, 0.f);
    float4 a1 = make_float4(0.f, 0.f, 0.f, 0.f);
    int e = 0;
    for (; e + 2 <= np; e += 2) {
        H4 u0, u1;
        u0.u = *(const uint2*)&xT[(size_t)sidx[e + 0] * Bsz + c];
        u1.u = *(const uint2*)&xT[(size_t)sidx[e + 1] * Bsz + c];
        const float2 f00 = __half22float2(u0.h[0]);
        const float2 f01 = __half22float2(u0.h[1]);
        const float2 f10 = __half22float2(u1.h[0]);
        const float2 f11 = __half22float2(u1.h[1]);
        a0.x += f00.x; a0.y += f00.y; a0.z += f01.x; a0.w += f01.y;
        a1.x += f10.x; a1.y += f10.y; a1.z += f11.x; a1.w += f11.y;
    }
    if (e < np) {
        H4 u;
        u.u = *(const uint2*)&xT[(size_t)sidx[e] * Bsz + c];
        const float2 f0 = __half22float2(u.h[0]);
        const float2 f1 = __half22float2(u.h[1]);
        a0.x += f0.x; a0.y += f0.y; a0.z += f1.x; a0.w += f1.y;
    }
    for (int ee = MAXIDX; ee < n; ++ee) {   // overflow fallback (never in practice)
        H4 u;
        u.u = *(const uint2*)&xT[(size_t)csr[beg + ee] * Bsz + c];
        const float2 f0 = __half22float2(u.h[0]);
        const float2 f1 = __half22float2(u.h[1]);
        a0.x += f0.x; a0.y += f0.y; a0.z += f1.x; a0.w += f1.y;
    }
    a0.x += a1.x; a0.y += a1.y; a0.z += a1.z; a0.w += a1.w;

    const float inv = 1.0f / fmaxf((float)n, 1.0f);
    const float sc = (pnext ? pnext[j] : 1.0f) * inv;   // relu(sum)*inv*pn == relu(sum*inv)*pn
    H4 o;
    o.h[0] = __floats2half2_rn(fmaxf(a0.x, 0.f) * sc, fmaxf(a0.y, 0.f) * sc);
    o.h[1] = __floats2half2_rn(fmaxf(a0.z, 0.f) * sc, fmaxf(a0.w, 0.f) * sc);
    *(uint2*)&yT[(size_t)j * Bsz + c] = o.u;
}

// ---------------------------------------------------------------------------
// Head: out (B,10) = y2 (B,256) @ W.T + b, y2 stored transposed as fp16.
__global__ __launch_bounds__(256) void head_gemm(
    const __half* __restrict__ y2T, const float* __restrict__ W,
    const float* __restrict__ bias, float* __restrict__ out)
{
    __shared__ float ws[10 * 256];
    __shared__ float bs[10];
    const int t = threadIdx.x;
    for (int i = t; i < 10 * 256; i += 256) ws[i] = W[i];
    if (t < 10) bs[t] = bias[t];
    __syncthreads();

    const int b = blockIdx.x * 256 + t;
    float acc[10];
#pragma unroll
    for (int o = 0; o < 10; ++o) acc[o] = bs[o];
    for (int k = 0; k < 256; ++k) {
        const float v = __half2float(y2T[(size_t)k * Bsz + b]);
#pragma unroll
        for (int o = 0; o < 10; ++o) acc[o] += v * ws[o * 256 + k];
    }
#pragma unroll
    for (int o = 0; o < 10; ++o) out[(size_t)b * 10 + o] = acc[o];
}

// ---------------------------------------------------------------------------
extern "C" void kernel_launch(void* const* d_in, const int* in_sizes, int n_in,
                              void* d_out, int out_size, void* d_ws, size_t ws_size,
                              hipStream_t stream)
{
    const float* data = (const float*)d_in[0];
    const float* p0   = (const float*)d_in[1];
    const float* p1   = (const float*)d_in[2];
    const float* p2   = (const float*)d_in[3];
    const float* W    = (const float*)d_in[4];
    const float* bias = (const float*)d_in[5];
    const int* src0 = (const int*)d_in[6];
    const int* dst0 = (const int*)d_in[7];
    const int* src1 = (const int*)d_in[8];
    const int* dst1 = (const int*)d_in[9];
    const int* src2 = (const int*)d_in[10];
    const int* dst2 = (const int*)d_in[11];

    char* ws = (char*)d_ws;
    auto align = [](size_t x) { return (x + 255) & ~size_t(255); };
    size_t o = 0;
    __half* dataT = (__half*)(ws + o); o = align(o + (size_t)F0 * Bsz * 2);
    __half* y0    = (__half*)(ws + o); o = align(o + (size_t)NOUT0 * Bsz * 2);
    __half* y1    = (__half*)(ws + o); o = align(o + (size_t)NOUT1 * Bsz * 2);
    __half* y2    = (__half*)(ws + o); o = align(o + (size_t)NOUT2 * Bsz * 2);
    int* cnt      = (int*)(ws + o);    o = align(o + (size_t)CNT_N * 4);
    int* offs     = (int*)(ws + o);    o = align(o + (size_t)OFFS_N * 4);
    int* cursor   = (int*)(ws + o);    o = align(o + (size_t)CNT_N * 4);
    int* csr      = (int*)(ws + o);    o = align(o + (size_t)CSR_N * 4);

    hipMemsetAsync(cnt, 0, (size_t)CNT_N * 4, stream);

    constexpr int totE = NE0 + NE1 + NE2;
    count_edges<<<(totE + 255) / 256, 256, 0, stream>>>(dst0, dst1, dst2, cnt);
    scan_offs<<<3, 1024, 0, stream>>>(cnt, offs, cursor);
    scatter_edges<<<(totE + 255) / 256, 256, 0, stream>>>(
        src0, dst0, src1, dst1, src2, dst2, cursor, csr);

    transpose_scale<<<dim3((F0 + 63) / 64, Bsz / 64), 256, 0, stream>>>(data, p0, dataT);

    layer_fwd<<<NOUT0, 256, 0, stream>>>(dataT, csr, offs, p1, y0);
    layer_fwd<<<NOUT1, 256, 0, stream>>>(y0, csr + NE0, offs + NOUT0 + 1, p2, y1);
    layer_fwd<<<NOUT2, 256, 0, stream>>>(y1, csr + NE0 + NE1, offs + NOUT0 + NOUT1 + 2,
                                         nullptr, y2);

    head_gemm<<<Bsz / 256, 256, 0, stream>>>(y2, W, bias, (float*)d_out);
}